// Round 11
// baseline (932.377 us; speedup 1.0000x reference)
//
#include <hip/hip_runtime.h>
#include <math.h>

// Problem constants
#define Bn   8
#define Sn   1024
#define Dn   512
#define Hn   8
#define DKn  64
#define Ln   6
#define DFFn 2048
#define Mn   (Bn * Sn)   // 8192 rows

typedef __bf16 bf16x8 __attribute__((ext_vector_type(8)));
typedef __bf16 bf16x4 __attribute__((ext_vector_type(4)));
typedef float  f32x4  __attribute__((ext_vector_type(4)));

// async global->LDS, 16B per lane. LDS dest must be wave-uniform base + lane*16.
__device__ __forceinline__ void gl_lds16(const void* g, void* l) {
    __builtin_amdgcn_global_load_lds(
        (const __attribute__((address_space(1))) void*)g,
        (__attribute__((address_space(3))) void*)l, 16, 0, 0);
}

// ---------------------------------------------------------------------------
// fp32 -> bf16 cast (input)
// ---------------------------------------------------------------------------
__global__ __launch_bounds__(256) void k_cast_bf16(const float* __restrict__ in,
                                                   __bf16* __restrict__ out, int n) {
    int i = blockIdx.x * 256 + threadIdx.x;
    if (i < n) out[i] = (__bf16)in[i];
}

// ---------------------------------------------------------------------------
// ALL weight matrices of ALL 6 layers: W[K][N] fp32 -> Wt[N][K] bf16.
// One launch (weights are layer-loop invariant). 32x32 tiles, 32x8 threads.
// ---------------------------------------------------------------------------
__global__ __launch_bounds__(256) void k_trans_all(
    const float* __restrict__ qkv_w, const float* __restrict__ out_w,
    const float* __restrict__ w1, const float* __restrict__ w2,
    __bf16* __restrict__ Wq, __bf16* __restrict__ Wo,
    __bf16* __restrict__ W1o, __bf16* __restrict__ W2o)
{
    const int lay = blockIdx.x / 3072;
    const int t   = blockIdx.x % 3072;
    const float* src; __bf16* dst; int K, N, n0, k0;
    if (t < 768)       { src = qkv_w + (size_t)lay * Dn * 3 * Dn; dst = Wq  + (size_t)lay * 3 * Dn * Dn;
                         K = 512;  N = 1536; int u = t;        n0 = (u % 48) * 32; k0 = (u / 48) * 32; }
    else if (t < 1024) { src = out_w + (size_t)lay * Dn * Dn;     dst = Wo  + (size_t)lay * Dn * Dn;
                         K = 512;  N = 512;  int u = t - 768;  n0 = (u % 16) * 32; k0 = (u / 16) * 32; }
    else if (t < 2048) { src = w1 + (size_t)lay * Dn * DFFn;      dst = W1o + (size_t)lay * DFFn * Dn;
                         K = 512;  N = 2048; int u = t - 1024; n0 = (u % 64) * 32; k0 = (u / 64) * 32; }
    else               { src = w2 + (size_t)lay * DFFn * Dn;      dst = W2o + (size_t)lay * Dn * DFFn;
                         K = 2048; N = 512;  int u = t - 2048; n0 = (u % 16) * 32; k0 = (u / 16) * 32; }

    __shared__ float tt[32][33];
    const int tx = threadIdx.x, ty = threadIdx.y;
    #pragma unroll
    for (int r = 0; r < 4; r++)
        tt[ty + 8 * r][tx] = src[(size_t)(k0 + ty + 8 * r) * N + n0 + tx];
    __syncthreads();
    #pragma unroll
    for (int r = 0; r < 4; r++)
        dst[(size_t)(n0 + ty + 8 * r) * K + k0 + tx] = (__bf16)tt[tx][ty + 8 * r];
}

// ---------------------------------------------------------------------------
// MFMA GEMM: C[M,N] = act(A[M,K]bf16 @ Bt[N,K]bf16^T + bias[N]fp32)
// Block: 256 thr = 4 waves (2x2). Tile: 128 x (JT*32). K-step: BK (64 or 128).
// (a) 1D grid + bijective chunked XCD swizzle.
// (b) XOR LDS swizzle both-sides (rule #21): unit u' = u ^ (row & (UR-1)).
// BK=128 on JT=2 kernels: halved barrier-drain count (R7/R10 evidence:
// step count is THE cost for these grid-limited latency-bound GEMMs;
// R10's BK=64+dbuf attempt regressed +60us -> reverted to R9 structure).
// SPLITK=1 (MLP-down): grid doubles, halves of the grid (XCD 0-3 / 4-7)
// each compute K/2 and write fp32 partials to Cout + sk*Mn*Dn; bias added
// by half-0 only; the following LN sums t0+t1+x (exact reassociation).
// VW=1 (QKV only): cols >=1024 are V -> ONLY scattered into Vt.
// ---------------------------------------------------------------------------
template <int RELU, int OUTBF, int JT, int VW, int BK, int SPLITK>
__global__ __launch_bounds__(256) void k_gemm_mfma(
    const __bf16* __restrict__ A, const __bf16* __restrict__ Bt,
    const float* __restrict__ bias, void* __restrict__ Cout,
    __bf16* __restrict__ Vt, int M, int N, int K, int NBX)
{
    constexpr int BN = JT * 32;   // 128 or 64
    constexpr int UR = BK / 8;    // 16B units per LDS row
    constexpr int HC = BK / 32;   // K=32 chunks per K-step
    __shared__ __bf16 As[128][BK];
    __shared__ __bf16 Bs[BN][BK];
    const int tid  = threadIdx.x;
    const int lane = tid & 63;
    const int wave = tid >> 6;
    const int wy   = wave >> 1, wx = wave & 1;
    const int m16  = lane & 15, quad = lane >> 4;

    // chunked XCD swizzle (all launches have gridDim.x % 8 == 0)
    const int cpx = gridDim.x >> 3;
    int id = (blockIdx.x & 7) * cpx + (blockIdx.x >> 3);
    int sk = 0;
    if constexpr (SPLITK) {
        const int half = gridDim.x >> 1;
        if (id >= half) { sk = 1; id -= half; }
    }
    const int bm  = (id / NBX) * 128;
    const int bn  = (id % NBX) * BN;
    const int KL   = SPLITK ? (K >> 1) : K;    // per-block K extent
    const int koff = SPLITK ? sk * KL : 0;

    f32x4 acc[4][JT];
    #pragma unroll
    for (int i = 0; i < 4; i++)
        #pragma unroll
        for (int j = 0; j < JT; j++)
            acc[i][j] = (f32x4){0.f, 0.f, 0.f, 0.f};

    const __bf16* Ap = A  + (size_t)bm * K + koff;
    const __bf16* Bp = Bt + (size_t)bn * K + koff;

    // swizzled 16B-unit byte offsets for fragment reads (involution of stage)
    int sw[HC];
    #pragma unroll
    for (int hc = 0; hc < HC; hc++)
        sw[hc] = ((quad + 4 * hc) ^ (m16 & (UR - 1))) * 8;

    for (int k0 = 0; k0 < KL; k0 += BK) {
        __syncthreads();
        #pragma unroll
        for (int c = 0; c < UR / 2; c++) {        // A: 128 x UR units
            int lin = tid + c * 256;
            int row = lin / UR, uu = lin % UR;
            int su  = (uu ^ (row & (UR - 1))) << 3;
            gl_lds16(Ap + (size_t)row * K + k0 + su, (void*)(&As[0][0] + lin * 8));
        }
        #pragma unroll
        for (int c = 0; c < (JT * UR) / 8; c++) { // B: BN x UR units
            int lin = tid + c * 256;
            int row = lin / UR, uu = lin % UR;
            int su  = (uu ^ (row & (UR - 1))) << 3;
            gl_lds16(Bp + (size_t)row * K + k0 + su, (void*)(&Bs[0][0] + lin * 8));
        }
        __syncthreads();

        bf16x8 af[4][HC], bfr[JT][HC];
        #pragma unroll
        for (int i = 0; i < 4; i++)
            #pragma unroll
            for (int hc = 0; hc < HC; hc++)
                af[i][hc] = *(const bf16x8*)&As[wy * 64 + i * 16 + m16][sw[hc]];
        #pragma unroll
        for (int j = 0; j < JT; j++)
            #pragma unroll
            for (int hc = 0; hc < HC; hc++)
                bfr[j][hc] = *(const bf16x8*)&Bs[wx * JT * 16 + j * 16 + m16][sw[hc]];
        #pragma unroll
        for (int hc = 0; hc < HC; hc++)
            #pragma unroll
            for (int i = 0; i < 4; i++)
                #pragma unroll
                for (int j = 0; j < JT; j++)
                    acc[i][j] = __builtin_amdgcn_mfma_f32_16x16x32_bf16(
                        af[i][hc], bfr[j][hc], acc[i][j], 0, 0, 0);
    }

    float*  Cf = (float*)Cout + (SPLITK ? (size_t)sk * Mn * Dn : 0);
    __bf16* Cb = (__bf16*)Cout;
    #pragma unroll
    for (int i = 0; i < 4; i++) {
        const int row0 = bm + wy * 64 + i * 16 + quad * 4;
        #pragma unroll
        for (int j = 0; j < JT; j++) {
            const int col = bn + wx * JT * 16 + j * 16 + m16;
            const float bv = (SPLITK && sk) ? 0.f : bias[col];
            float vv[4];
            #pragma unroll
            for (int r = 0; r < 4; r++) {
                float v = acc[i][j][r] + bv;
                if (RELU) v = fmaxf(v, 0.f);
                vv[r] = v;
                if (!VW || col < 1024) {       // V region is only stored to Vt
                    if (OUTBF) Cb[(size_t)(row0 + r) * N + col] = (__bf16)v;
                    else       Cf[(size_t)(row0 + r) * N + col] = v;
                }
            }
            if (VW && col >= 1024) {            // V slice -> Vt[b*8+h][d][s]
                const int cc = col - 1024;
                const int bb = row0 >> 10, ss = row0 & 1023;
                bf16x4 pv;
                #pragma unroll
                for (int r = 0; r < 4; r++) pv[r] = (__bf16)vv[r];
                *(bf16x4*)&Vt[((size_t)(bb * Hn + (cc >> 6)) * DKn + (cc & 63)) * Sn + ss] = pv;
            }
        }
    }
}

// ---------------------------------------------------------------------------
// MFMA flash attention (causal), LDS-staged K/V, wave-split tile pair,
// counted vmcnt (T4), SWAPPED QK^T (T12-style lane-local softmax).
// S' = mfma(K_frag, Q_frag): C/D is S'[k=quad*4+r (+j*16)][q=m16]; each
// thread owns one q-row's softmax (scalar m/l, 2 shfl_xor reduce); P-store
// is 4x contiguous 8B; exp in log2 domain. PV reads P as the A-fragment.
// ---------------------------------------------------------------------------
__device__ __forceinline__ void softmax_update_sw(
    f32x4 sv[4], float& m, float& l, f32x4 acc[4],
    bool diag, int wave16, int quad, int m16,
    __bf16 (*Pw)[72], bf16x8& pf0, bf16x8& pf1)
{
    const float SC = 0.125f * 1.44269504089f;   // 1/sqrt(64) * log2(e)
    float pmax = -1e30f;
    #pragma unroll
    for (int j = 0; j < 4; j++)
        #pragma unroll
        for (int r = 0; r < 4; r++) {
            float v = sv[j][r] * SC;
            if (diag && (j * 16 + quad * 4 + r) > (wave16 + m16)) v = -1e30f;
            sv[j][r] = v;
            pmax = fmaxf(pmax, v);
        }
    // cross-quad reduce: lanes {m16, m16+16, m16+32, m16+48} share q=m16
    pmax = fmaxf(pmax, __shfl_xor(pmax, 16));
    pmax = fmaxf(pmax, __shfl_xor(pmax, 32));

    // T13 defer-max (log2 domain; 11.54 = 8*log2e -> P bounded by e^8)
    if (__any((int)(pmax > m + 11.54f))) {
        float mn = fmaxf(m, pmax);
        float al = __builtin_amdgcn_exp2f(m - mn);
        m = mn;
        l *= al;
        float alr[4];
        #pragma unroll
        for (int r = 0; r < 4; r++) alr[r] = __shfl(al, quad * 4 + r, 16);
        #pragma unroll
        for (int j = 0; j < 4; j++)
            #pragma unroll
            for (int r = 0; r < 4; r++) acc[j][r] *= alr[r];
    }

    float rs = 0.f;
    #pragma unroll
    for (int j = 0; j < 4; j++) {
        bf16x4 pw;
        #pragma unroll
        for (int r = 0; r < 4; r++) {
            float p = __builtin_amdgcn_exp2f(sv[j][r] - m);
            rs += p;
            pw[r] = (__bf16)p;
        }
        *(bf16x4*)&Pw[m16][j * 16 + quad * 4] = pw;   // contiguous 8B store
    }
    rs += __shfl_xor(rs, 16);
    rs += __shfl_xor(rs, 32);
    l += rs;

    // per-wave in-order DS: the 4 writes above retire before these reads
    pf0 = *(const bf16x8*)&Pw[m16][quad * 8];
    pf1 = *(const bf16x8*)&Pw[m16][32 + quad * 8];
}

__global__ __launch_bounds__(512, 4) void k_attn_mfma(
    const __bf16* __restrict__ qkv, const __bf16* __restrict__ Vt,
    __bf16* __restrict__ o)
{
    const int id = blockIdx.x;
    const int u  = id >> 6;            // 0..7
    const int pr = (u < 4) ? u : 11 - u;   // CU-pair balance: steps sum to 25
    const int b  = (id >> 3) & 7;
    const int h  = id & 7;             // id%8 = h -> blocks of one h share an XCD
    const int tid  = threadIdx.x;
    const int lane = tid & 63, wave = tid >> 6;   // 0..7
    const int m16  = lane & 15, quad = lane >> 4;
    const int isB  = wave >> 2;        // 0: tile A (qtA=pr), 1: tile B (qtB=15-pr)
    const int wave16 = (wave & 3) * 16;
    const int qtA  = pr, qtB = 15 - pr;
    const int qt   = isB ? qtB : qtA;

    __shared__ __bf16 Kb[2][64][64];     // double-buffered K tile (swizzled)
    __shared__ __bf16 Vb[2][64][64];     // double-buffered V tile (swizzled)
    __shared__ __bf16 Ps[8][16][72];     // per-wave P scratch

    const __bf16* base = qkv + (size_t)b * Sn * 1536 + h * DKn;   // Q +0, K +512
    const __bf16* vtb  = Vt + (size_t)(b * Hn + h) * DKn * Sn;
    __bf16 (*Pw)[72] = Ps[wave];

    // swizzled 16B-unit offsets for fragment reads (involution of stage swizzle)
    const int sw0 = ((quad    ) ^ (m16 & 7)) * 8;
    const int sw1 = ((quad + 4) ^ (m16 & 7)) * 8;

    // staging coords: 512 threads x 16B cover one 64x64 bf16 tile per call.
    // Exactly 2 VMEM ops per thread per STAGE (1 K + 1 V).
    const int srow = tid >> 3;
    const int ssu  = ((tid & 7) ^ (srow & 7)) * 8;

    #define STAGE(KT, BB)                                                       \
        {                                                                       \
            gl_lds16(base + (size_t)((KT) * 64 + srow) * 1536 + 512 + ssu,      \
                     (void*)(&Kb[BB][0][0] + tid * 8));                         \
            gl_lds16(vtb + (size_t)srow * Sn + (KT) * 64 + ssu,                 \
                     (void*)(&Vb[BB][0][0] + tid * 8));                         \
        }

    STAGE(0, 0);   // issue tile-0 staging first; Q loads overlap it

    bf16x8 q0, q1;
    {
        const __bf16* qa = base + (size_t)(qt * 64 + wave16 + m16) * 1536 + quad * 8;
        q0 = *(const bf16x8*)qa; q1 = *(const bf16x8*)(qa + 32);
    }

    float m = -1e30f, l = 0.f;
    f32x4 acc[4];
    #pragma unroll
    for (int r = 0; r < 4; r++) acc[r] = (f32x4){0.f, 0.f, 0.f, 0.f};

    for (int kt = 0; kt <= qtB; kt++) {
        const int buf = kt & 1;
        // issue next-tile staging, then wait only for CURRENT tile's loads:
        // exactly 2 loads (the new stage) remain outstanding across the barrier.
        if (kt < qtB) {
            STAGE(kt + 1, buf ^ 1);
            asm volatile("s_waitcnt vmcnt(2)" ::: "memory");
        } else {
            asm volatile("s_waitcnt vmcnt(0)" ::: "memory");
        }
        __builtin_amdgcn_s_barrier();   // cur buf fully written, all waves aligned

        if (isB || kt <= qtA) {
            // ---- S' = K Q^T from LDS (swapped operands; loads unchanged) ----
            f32x4 sv[4];
            __builtin_amdgcn_s_setprio(1);
            #pragma unroll
            for (int j = 0; j < 4; j++) {
                const int rk = j * 16 + m16;
                bf16x8 kf0 = *(const bf16x8*)&Kb[buf][rk][sw0];
                bf16x8 kf1 = *(const bf16x8*)&Kb[buf][rk][sw1];
                f32x4 s = (f32x4){0.f, 0.f, 0.f, 0.f};
                s = __builtin_amdgcn_mfma_f32_16x16x32_bf16(kf0, q0, s, 0, 0, 0);
                s = __builtin_amdgcn_mfma_f32_16x16x32_bf16(kf1, q1, s, 0, 0, 0);
                sv[j] = s;
            }
            __builtin_amdgcn_s_setprio(0);

            // ---- V fragments from LDS (issued before softmax; latency hides) ----
            bf16x8 vf[4][2];
            #pragma unroll
            for (int jd = 0; jd < 4; jd++) {
                const int rv = jd * 16 + m16;
                vf[jd][0] = *(const bf16x8*)&Vb[buf][rv][sw0];
                vf[jd][1] = *(const bf16x8*)&Vb[buf][rv][sw1];
            }

            // ---- online softmax (lane-local q-row, scalar m/l) ----
            bf16x8 p0, p1;
            softmax_update_sw(sv, m, l, acc, kt == qt, wave16, quad, m16, Pw, p0, p1);

            // ---- O += P V ----
            __builtin_amdgcn_s_setprio(1);
            #pragma unroll
            for (int jd = 0; jd < 4; jd++) {
                acc[jd] = __builtin_amdgcn_mfma_f32_16x16x32_bf16(p0, vf[jd][0], acc[jd], 0, 0, 0);
                acc[jd] = __builtin_amdgcn_mfma_f32_16x16x32_bf16(p1, vf[jd][1], acc[jd], 0, 0, 0);
            }
            __builtin_amdgcn_s_setprio(0);
        }

        // my ds ops retired -> after the barrier the buffers may be overwritten
        asm volatile("s_waitcnt lgkmcnt(0)" ::: "memory");
        __builtin_amdgcn_s_barrier();
    }
    #undef STAGE

    // epilogue: O / l — l lives at lane q=m16; acc rows are q=quad*4+r
    float linv[4];
    #pragma unroll
    for (int r = 0; r < 4; r++) linv[r] = 1.0f / __shfl(l, quad * 4 + r, 16);
    #pragma unroll
    for (int jd = 0; jd < 4; jd++)
        #pragma unroll
        for (int r = 0; r < 4; r++) {
            const int row = b * Sn + qt * 64 + wave16 + quad * 4 + r;
            o[(size_t)row * Dn + h * DKn + jd * 16 + m16] = (__bf16)(acc[jd][r] * linv[r]);
        }
}

// ---------------------------------------------------------------------------
// Residual + LayerNorm, wave-per-row, barrier-free.
// Lane owns 8 consecutive cols (bf16x8/f32x4 loads). 64-lane shfl_xor reduce.
// SPLIT=0: t = bf16 temp.  SPLIT=1: t = two fp32 partials (t0, t0+Mn*Dn).
// FINAL=0: xb = LN(t + xb) (bf16). FINAL=1: outf = LN(t + xb) (fp32).
// ---------------------------------------------------------------------------
template <int FINAL, int SPLIT>
__global__ __launch_bounds__(256) void k_residual_ln(
    const void* __restrict__ t_, __bf16* __restrict__ xb,
    const float* __restrict__ g, const float* __restrict__ be,
    float* __restrict__ outf)
{
    const int row  = (blockIdx.x << 2) | (threadIdx.x >> 6);  // 4 rows/block
    const int lane = threadIdx.x & 63;
    const size_t base = (size_t)row * Dn + lane * 8;

    bf16x8 xv = *(const bf16x8*)&xb[base];
    float v[8];
    float s = 0.f;
    if constexpr (SPLIT) {
        const float* t0 = (const float*)t_;
        const float* t1 = t0 + (size_t)Mn * Dn;
        f32x4 a0 = *(const f32x4*)&t0[base], a1 = *(const f32x4*)&t0[base + 4];
        f32x4 c0 = *(const f32x4*)&t1[base], c1 = *(const f32x4*)&t1[base + 4];
        #pragma unroll
        for (int i = 0; i < 4; i++) {
            v[i]     = a0[i] + c0[i] + (float)xv[i];
            v[i + 4] = a1[i] + c1[i] + (float)xv[i + 4];
        }
    } else {
        const __bf16* tb = (const __bf16*)t_;
        bf16x8 tv = *(const bf16x8*)&tb[base];
        #pragma unroll
        for (int i = 0; i < 8; i++) v[i] = (float)tv[i] + (float)xv[i];
    }
    #pragma unroll
    for (int i = 0; i < 8; i++) s += v[i];
    #pragma unroll
    for (int off = 1; off < 64; off <<= 1) s += __shfl_xor(s, off);
    const float mean = s * (1.0f / Dn);

    float vs = 0.f;
    #pragma unroll
    for (int i = 0; i < 8; i++) {
        v[i] -= mean;
        vs += v[i] * v[i];
    }
    #pragma unroll
    for (int off = 1; off < 64; off <<= 1) vs += __shfl_xor(vs, off);
    const float inv = rsqrtf(vs * (1.0f / Dn) + 1e-5f);

    const f32x4 g0 = *(const f32x4*)&g[lane * 8];
    const f32x4 g1 = *(const f32x4*)&g[lane * 8 + 4];
    const f32x4 b0 = *(const f32x4*)&be[lane * 8];
    const f32x4 b1 = *(const f32x4*)&be[lane * 8 + 4];

    if (FINAL) {
        f32x4 o0, o1;
        #pragma unroll
        for (int i = 0; i < 4; i++) {
            o0[i] = v[i] * inv * g0[i] + b0[i];
            o1[i] = v[i + 4] * inv * g1[i] + b1[i];
        }
        *(f32x4*)&outf[base]     = o0;
        *(f32x4*)&outf[base + 4] = o1;
    } else {
        bf16x8 ov;
        #pragma unroll
        for (int i = 0; i < 4; i++) {
            ov[i]     = (__bf16)(v[i] * inv * g0[i] + b0[i]);
            ov[i + 4] = (__bf16)(v[i + 4] * inv * g1[i] + b1[i]);
        }
        *(bf16x8*)&xb[base] = ov;
    }
}

// ---------------------------------------------------------------------------
// launcher
// ---------------------------------------------------------------------------
extern "C" void kernel_launch(void* const* d_in, const int* in_sizes, int n_in,
                              void* d_out, int out_size, void* d_ws, size_t ws_size,
                              hipStream_t stream)
{
    const float* x_in   = (const float*)d_in[0];
    const float* qkv_w  = (const float*)d_in[1];
    const float* qkv_b  = (const float*)d_in[2];
    const float* out_w  = (const float*)d_in[3];
    const float* out_b  = (const float*)d_in[4];
    const float* ln1_g  = (const float*)d_in[5];
    const float* ln1_b  = (const float*)d_in[6];
    const float* mlp_w1 = (const float*)d_in[7];
    const float* mlp_b1 = (const float*)d_in[8];
    const float* mlp_w2 = (const float*)d_in[9];
    const float* mlp_b2 = (const float*)d_in[10];
    const float* ln2_g  = (const float*)d_in[11];
    const float* ln2_b  = (const float*)d_in[12];

    // workspace layout (~116 MB); residual lives in bf16 Xb only
    char* p = (char*)d_ws;
    __bf16* Xb    = (__bf16*)p; p += (size_t)Mn * Dn * 2;            //  8 MB
    __bf16* QKVb  = (__bf16*)p; p += (size_t)Mn * 3 * Dn * 2;        // 24 MB
    __bf16* AOb   = (__bf16*)p; p += (size_t)Mn * Dn * 2;            //  8 MB
    __bf16* Hb    = (__bf16*)p; p += (size_t)Mn * DFFn * 2;          // 32 MB
    __bf16* BUF3b = (__bf16*)p; p += (size_t)Mn * Dn * 2;            //  8 MB pre-LN temp
    __bf16* Wq    = (__bf16*)p; p += (size_t)Ln * 3 * Dn * Dn * 2;   //  9 MB
    __bf16* Wo    = (__bf16*)p; p += (size_t)Ln * Dn * Dn * 2;       //  3 MB
    __bf16* W1    = (__bf16*)p; p += (size_t)Ln * DFFn * Dn * 2;     // 12 MB
    __bf16* W2    = (__bf16*)p; p += (size_t)Ln * Dn * DFFn * 2;     // 12 MB
    __bf16* Vt    = Hb;              // 8 MB, aliased: Hb dead during attention
    float*  T01   = (float*)QKVb;    // 32 MB fp32 split-K partials, aliased over
                                     // QKVb+AOb (both dead by MLP-down time)

    k_cast_bf16<<<(Mn * Dn) / 256, 256, 0, stream>>>(x_in, Xb, Mn * Dn);

    // ALL weight transposes for all 6 layers in one launch (loop-invariant)
    k_trans_all<<<Ln * 3072, dim3(32, 8), 0, stream>>>(
        qkv_w, out_w, mlp_w1, mlp_w2, Wq, Wo, W1, W2);

    for (int l = 0; l < Ln; l++) {
        const __bf16* Wql = Wq + (size_t)l * 3 * Dn * Dn;
        const __bf16* Wol = Wo + (size_t)l * Dn * Dn;
        const __bf16* W1l = W1 + (size_t)l * DFFn * Dn;
        const __bf16* W2l = W2 + (size_t)l * Dn * DFFn;

        // QKV projection -> bf16 [M,1536] + fused Vt scatter (V only to Vt)
        k_gemm_mfma<0, 1, 4, 1, 64, 0><<<768, 256, 0, stream>>>(
            Xb, Wql, qkv_b + (size_t)l * 3 * Dn, QKVb, Vt, Mn, 3 * Dn, Dn, 12);
        // MFMA flash attention (pair split, counted vmcnt, swapped QK) -> bf16
        k_attn_mfma<<<512, 512, 0, stream>>>(QKVb, Vt, AOb);
        // output projection -> bf16 BUF3b  (BK=128: halved barrier drains)
        k_gemm_mfma<0, 1, 2, 0, 128, 0><<<512, 256, 0, stream>>>(
            AOb, Wol, out_b + (size_t)l * Dn, BUF3b, nullptr, Mn, Dn, Dn, 8);
        // x = LN(proj + x)   (bf16 in/out, fp32 math, wave-per-row)
        k_residual_ln<0, 0><<<Mn / 4, 256, 0, stream>>>(BUF3b, Xb,
            ln1_g + (size_t)l * Dn, ln1_b + (size_t)l * Dn, nullptr);
        // MLP up + ReLU -> bf16 [M,2048]  (overwrites Vt alias; attn done)
        k_gemm_mfma<1, 1, 4, 0, 64, 0><<<1024, 256, 0, stream>>>(
            Xb, W1l, mlp_b1 + (size_t)l * DFFn, Hb, nullptr, Mn, DFFn, Dn, 16);
        // MLP down, split-K=2 -> fp32 partials T01[0], T01[1]  (BK=128)
        // (T01 aliases QKVb+AOb: both dead here; bias added by half-0 only)
        k_gemm_mfma<0, 0, 2, 0, 128, 1><<<1024, 256, 0, stream>>>(
            Hb, W2l, mlp_b2 + (size_t)l * Dn, T01, nullptr, Mn, Dn, DFFn, 8);
        // x = LN(t0 + t1 + x); final layer writes fp32 straight to d_out
        if (l == Ln - 1)
            k_residual_ln<1, 1><<<Mn / 4, 256, 0, stream>>>(T01, Xb,
                ln2_g + (size_t)l * Dn, ln2_b + (size_t)l * Dn, (float*)d_out);
        else
            k_residual_ln<0, 1><<<Mn / 4, 256, 0, stream>>>(T01, Xb,
                ln2_g + (size_t)l * Dn, ln2_b + (size_t)l * Dn, nullptr);
    }
}

// Round 12
// 880.526 us; speedup vs baseline: 1.0589x; 1.0589x over previous
//
#include <hip/hip_runtime.h>
#include <math.h>

// Problem constants
#define Bn   8
#define Sn   1024
#define Dn   512
#define Hn   8
#define DKn  64
#define Ln   6
#define DFFn 2048
#define Mn   (Bn * Sn)   // 8192 rows

typedef __bf16 bf16x8 __attribute__((ext_vector_type(8)));
typedef __bf16 bf16x4 __attribute__((ext_vector_type(4)));
typedef float  f32x4  __attribute__((ext_vector_type(4)));

// async global->LDS, 16B per lane. LDS dest must be wave-uniform base + lane*16.
__device__ __forceinline__ void gl_lds16(const void* g, void* l) {
    __builtin_amdgcn_global_load_lds(
        (const __attribute__((address_space(1))) void*)g,
        (__attribute__((address_space(3))) void*)l, 16, 0, 0);
}

// ---------------------------------------------------------------------------
// fp32 -> bf16 cast (input)
// ---------------------------------------------------------------------------
__global__ __launch_bounds__(256) void k_cast_bf16(const float* __restrict__ in,
                                                   __bf16* __restrict__ out, int n) {
    int i = blockIdx.x * 256 + threadIdx.x;
    if (i < n) out[i] = (__bf16)in[i];
}

// ---------------------------------------------------------------------------
// ALL weight matrices of ALL 6 layers: W[K][N] fp32 -> Wt[N][K] bf16.
// One launch (weights are layer-loop invariant). 32x32 tiles, 32x8 threads.
// ---------------------------------------------------------------------------
__global__ __launch_bounds__(256) void k_trans_all(
    const float* __restrict__ qkv_w, const float* __restrict__ out_w,
    const float* __restrict__ w1, const float* __restrict__ w2,
    __bf16* __restrict__ Wq, __bf16* __restrict__ Wo,
    __bf16* __restrict__ W1o, __bf16* __restrict__ W2o)
{
    const int lay = blockIdx.x / 3072;
    const int t   = blockIdx.x % 3072;
    const float* src; __bf16* dst; int K, N, n0, k0;
    if (t < 768)       { src = qkv_w + (size_t)lay * Dn * 3 * Dn; dst = Wq  + (size_t)lay * 3 * Dn * Dn;
                         K = 512;  N = 1536; int u = t;        n0 = (u % 48) * 32; k0 = (u / 48) * 32; }
    else if (t < 1024) { src = out_w + (size_t)lay * Dn * Dn;     dst = Wo  + (size_t)lay * Dn * Dn;
                         K = 512;  N = 512;  int u = t - 768;  n0 = (u % 16) * 32; k0 = (u / 16) * 32; }
    else if (t < 2048) { src = w1 + (size_t)lay * Dn * DFFn;      dst = W1o + (size_t)lay * DFFn * Dn;
                         K = 512;  N = 2048; int u = t - 1024; n0 = (u % 64) * 32; k0 = (u / 64) * 32; }
    else               { src = w2 + (size_t)lay * DFFn * Dn;      dst = W2o + (size_t)lay * Dn * DFFn;
                         K = 2048; N = 512;  int u = t - 2048; n0 = (u % 16) * 32; k0 = (u / 16) * 32; }

    __shared__ float tt[32][33];
    const int tx = threadIdx.x, ty = threadIdx.y;
    #pragma unroll
    for (int r = 0; r < 4; r++)
        tt[ty + 8 * r][tx] = src[(size_t)(k0 + ty + 8 * r) * N + n0 + tx];
    __syncthreads();
    #pragma unroll
    for (int r = 0; r < 4; r++)
        dst[(size_t)(n0 + ty + 8 * r) * K + k0 + tx] = (__bf16)tt[tx][ty + 8 * r];
}

// ---------------------------------------------------------------------------
// MFMA GEMM: C[M,N] = act(A[M,K]bf16 @ Bt[N,K]bf16^T + bias[N]fp32)
// Block: 256 thr = 4 waves (2x2). Tile: 128 x (JT*32). K-step: BK (64 or 128).
// (a) 1D grid + bijective chunked XCD swizzle.
// (b) XOR LDS swizzle both-sides (rule #21): unit u' = u ^ (row & (UR-1)).
// BK=128 on JT=2 kernels (outproj/MLP-down, grid-limited 2 blocks/CU):
// halved barrier-drain count. R7/R10/R11 evidence: step count is THE cost
// for these latency-bound GEMMs; dbuf (R10) and split-K (R11) both lost
// to this plain structure.
// VW=1 (QKV only): cols >=1024 are V -> ONLY scattered into Vt (QKVb's V
// region is never read by attn; saves 8MB stores/layer).
// ---------------------------------------------------------------------------
template <int RELU, int OUTBF, int JT, int VW, int BK>
__global__ __launch_bounds__(256) void k_gemm_mfma(
    const __bf16* __restrict__ A, const __bf16* __restrict__ Bt,
    const float* __restrict__ bias, void* __restrict__ Cout,
    __bf16* __restrict__ Vt, int M, int N, int K, int NBX)
{
    constexpr int BN = JT * 32;   // 128 or 64
    constexpr int UR = BK / 8;    // 16B units per LDS row
    constexpr int HC = BK / 32;   // K=32 chunks per K-step
    __shared__ __bf16 As[128][BK];
    __shared__ __bf16 Bs[BN][BK];
    const int tid  = threadIdx.x;
    const int lane = tid & 63;
    const int wave = tid >> 6;
    const int wy   = wave >> 1, wx = wave & 1;
    const int m16  = lane & 15, quad = lane >> 4;

    // chunked XCD swizzle (all launches have gridDim.x % 8 == 0)
    const int cpx = gridDim.x >> 3;
    const int id  = (blockIdx.x & 7) * cpx + (blockIdx.x >> 3);
    const int bm  = (id / NBX) * 128;
    const int bn  = (id % NBX) * BN;

    f32x4 acc[4][JT];
    #pragma unroll
    for (int i = 0; i < 4; i++)
        #pragma unroll
        for (int j = 0; j < JT; j++)
            acc[i][j] = (f32x4){0.f, 0.f, 0.f, 0.f};

    const __bf16* Ap = A  + (size_t)bm * K;
    const __bf16* Bp = Bt + (size_t)bn * K;

    // swizzled 16B-unit byte offsets for fragment reads (involution of stage)
    int sw[HC];
    #pragma unroll
    for (int hc = 0; hc < HC; hc++)
        sw[hc] = ((quad + 4 * hc) ^ (m16 & (UR - 1))) * 8;

    for (int k0 = 0; k0 < K; k0 += BK) {
        __syncthreads();
        #pragma unroll
        for (int c = 0; c < UR / 2; c++) {        // A: 128 x UR units
            int lin = tid + c * 256;
            int row = lin / UR, uu = lin % UR;
            int su  = (uu ^ (row & (UR - 1))) << 3;
            gl_lds16(Ap + (size_t)row * K + k0 + su, (void*)(&As[0][0] + lin * 8));
        }
        #pragma unroll
        for (int c = 0; c < (JT * UR) / 8; c++) { // B: BN x UR units
            int lin = tid + c * 256;
            int row = lin / UR, uu = lin % UR;
            int su  = (uu ^ (row & (UR - 1))) << 3;
            gl_lds16(Bp + (size_t)row * K + k0 + su, (void*)(&Bs[0][0] + lin * 8));
        }
        __syncthreads();

        bf16x8 af[4][HC], bfr[JT][HC];
        #pragma unroll
        for (int i = 0; i < 4; i++)
            #pragma unroll
            for (int hc = 0; hc < HC; hc++)
                af[i][hc] = *(const bf16x8*)&As[wy * 64 + i * 16 + m16][sw[hc]];
        #pragma unroll
        for (int j = 0; j < JT; j++)
            #pragma unroll
            for (int hc = 0; hc < HC; hc++)
                bfr[j][hc] = *(const bf16x8*)&Bs[wx * JT * 16 + j * 16 + m16][sw[hc]];
        #pragma unroll
        for (int hc = 0; hc < HC; hc++)
            #pragma unroll
            for (int i = 0; i < 4; i++)
                #pragma unroll
                for (int j = 0; j < JT; j++)
                    acc[i][j] = __builtin_amdgcn_mfma_f32_16x16x32_bf16(
                        af[i][hc], bfr[j][hc], acc[i][j], 0, 0, 0);
    }

    float*  Cf = (float*)Cout;
    __bf16* Cb = (__bf16*)Cout;
    #pragma unroll
    for (int i = 0; i < 4; i++) {
        const int row0 = bm + wy * 64 + i * 16 + quad * 4;
        #pragma unroll
        for (int j = 0; j < JT; j++) {
            const int col = bn + wx * JT * 16 + j * 16 + m16;
            const float bv = bias[col];
            float vv[4];
            #pragma unroll
            for (int r = 0; r < 4; r++) {
                float v = acc[i][j][r] + bv;
                if (RELU) v = fmaxf(v, 0.f);
                vv[r] = v;
                if (!VW || col < 1024) {       // V region is only stored to Vt
                    if (OUTBF) Cb[(size_t)(row0 + r) * N + col] = (__bf16)v;
                    else       Cf[(size_t)(row0 + r) * N + col] = v;
                }
            }
            if (VW && col >= 1024) {            // V slice -> Vt[b*8+h][d][s]
                const int cc = col - 1024;
                const int bb = row0 >> 10, ss = row0 & 1023;
                bf16x4 pv;
                #pragma unroll
                for (int r = 0; r < 4; r++) pv[r] = (__bf16)vv[r];
                *(bf16x4*)&Vt[((size_t)(bb * Hn + (cc >> 6)) * DKn + (cc & 63)) * Sn + ss] = pv;
            }
        }
    }
}

// ---------------------------------------------------------------------------
// MFMA flash attention (causal), LDS-staged K/V, wave-split tile pair,
// counted vmcnt (T4), SWAPPED QK^T (T12-style lane-local softmax).
// S' = mfma(K_frag, Q_frag): C/D is S'[k=quad*4+r (+j*16)][q=m16]; each
// thread owns one q-row's softmax (scalar m/l, 2 shfl_xor reduce); P-store
// is 4x contiguous 8B; exp in log2 domain. PV reads P as the A-fragment.
// ---------------------------------------------------------------------------
__device__ __forceinline__ void softmax_update_sw(
    f32x4 sv[4], float& m, float& l, f32x4 acc[4],
    bool diag, int wave16, int quad, int m16,
    __bf16 (*Pw)[72], bf16x8& pf0, bf16x8& pf1)
{
    const float SC = 0.125f * 1.44269504089f;   // 1/sqrt(64) * log2(e)
    float pmax = -1e30f;
    #pragma unroll
    for (int j = 0; j < 4; j++)
        #pragma unroll
        for (int r = 0; r < 4; r++) {
            float v = sv[j][r] * SC;
            if (diag && (j * 16 + quad * 4 + r) > (wave16 + m16)) v = -1e30f;
            sv[j][r] = v;
            pmax = fmaxf(pmax, v);
        }
    // cross-quad reduce: lanes {m16, m16+16, m16+32, m16+48} share q=m16
    pmax = fmaxf(pmax, __shfl_xor(pmax, 16));
    pmax = fmaxf(pmax, __shfl_xor(pmax, 32));

    // T13 defer-max (log2 domain; 11.54 = 8*log2e -> P bounded by e^8)
    if (__any((int)(pmax > m + 11.54f))) {
        float mn = fmaxf(m, pmax);
        float al = __builtin_amdgcn_exp2f(m - mn);
        m = mn;
        l *= al;
        float alr[4];
        #pragma unroll
        for (int r = 0; r < 4; r++) alr[r] = __shfl(al, quad * 4 + r, 16);
        #pragma unroll
        for (int j = 0; j < 4; j++)
            #pragma unroll
            for (int r = 0; r < 4; r++) acc[j][r] *= alr[r];
    }

    float rs = 0.f;
    #pragma unroll
    for (int j = 0; j < 4; j++) {
        bf16x4 pw;
        #pragma unroll
        for (int r = 0; r < 4; r++) {
            float p = __builtin_amdgcn_exp2f(sv[j][r] - m);
            rs += p;
            pw[r] = (__bf16)p;
        }
        *(bf16x4*)&Pw[m16][j * 16 + quad * 4] = pw;   // contiguous 8B store
    }
    rs += __shfl_xor(rs, 16);
    rs += __shfl_xor(rs, 32);
    l += rs;

    // per-wave in-order DS: the 4 writes above retire before these reads
    pf0 = *(const bf16x8*)&Pw[m16][quad * 8];
    pf1 = *(const bf16x8*)&Pw[m16][32 + quad * 8];
}

__global__ __launch_bounds__(512, 4) void k_attn_mfma(
    const __bf16* __restrict__ qkv, const __bf16* __restrict__ Vt,
    __bf16* __restrict__ o)
{
    const int id = blockIdx.x;
    const int u  = id >> 6;            // 0..7
    const int pr = (u < 4) ? u : 11 - u;   // CU-pair balance: steps sum to 25
    const int b  = (id >> 3) & 7;
    const int h  = id & 7;             // id%8 = h -> blocks of one h share an XCD
    const int tid  = threadIdx.x;
    const int lane = tid & 63, wave = tid >> 6;   // 0..7
    const int m16  = lane & 15, quad = lane >> 4;
    const int isB  = wave >> 2;        // 0: tile A (qtA=pr), 1: tile B (qtB=15-pr)
    const int wave16 = (wave & 3) * 16;
    const int qtA  = pr, qtB = 15 - pr;
    const int qt   = isB ? qtB : qtA;

    __shared__ __bf16 Kb[2][64][64];     // double-buffered K tile (swizzled)
    __shared__ __bf16 Vb[2][64][64];     // double-buffered V tile (swizzled)
    __shared__ __bf16 Ps[8][16][72];     // per-wave P scratch

    const __bf16* base = qkv + (size_t)b * Sn * 1536 + h * DKn;   // Q +0, K +512
    const __bf16* vtb  = Vt + (size_t)(b * Hn + h) * DKn * Sn;
    __bf16 (*Pw)[72] = Ps[wave];

    // swizzled 16B-unit offsets for fragment reads (involution of stage swizzle)
    const int sw0 = ((quad    ) ^ (m16 & 7)) * 8;
    const int sw1 = ((quad + 4) ^ (m16 & 7)) * 8;

    // staging coords: 512 threads x 16B cover one 64x64 bf16 tile per call.
    // Exactly 2 VMEM ops per thread per STAGE (1 K + 1 V).
    const int srow = tid >> 3;
    const int ssu  = ((tid & 7) ^ (srow & 7)) * 8;

    #define STAGE(KT, BB)                                                       \
        {                                                                       \
            gl_lds16(base + (size_t)((KT) * 64 + srow) * 1536 + 512 + ssu,      \
                     (void*)(&Kb[BB][0][0] + tid * 8));                         \
            gl_lds16(vtb + (size_t)srow * Sn + (KT) * 64 + ssu,                 \
                     (void*)(&Vb[BB][0][0] + tid * 8));                         \
        }

    STAGE(0, 0);   // issue tile-0 staging first; Q loads overlap it

    bf16x8 q0, q1;
    {
        const __bf16* qa = base + (size_t)(qt * 64 + wave16 + m16) * 1536 + quad * 8;
        q0 = *(const bf16x8*)qa; q1 = *(const bf16x8*)(qa + 32);
    }

    float m = -1e30f, l = 0.f;
    f32x4 acc[4];
    #pragma unroll
    for (int r = 0; r < 4; r++) acc[r] = (f32x4){0.f, 0.f, 0.f, 0.f};

    for (int kt = 0; kt <= qtB; kt++) {
        const int buf = kt & 1;
        // issue next-tile staging, then wait only for CURRENT tile's loads:
        // exactly 2 loads (the new stage) remain outstanding across the barrier.
        if (kt < qtB) {
            STAGE(kt + 1, buf ^ 1);
            asm volatile("s_waitcnt vmcnt(2)" ::: "memory");
        } else {
            asm volatile("s_waitcnt vmcnt(0)" ::: "memory");
        }
        __builtin_amdgcn_s_barrier();   // cur buf fully written, all waves aligned

        if (isB || kt <= qtA) {
            // ---- S' = K Q^T from LDS (swapped operands; loads unchanged) ----
            f32x4 sv[4];
            __builtin_amdgcn_s_setprio(1);
            #pragma unroll
            for (int j = 0; j < 4; j++) {
                const int rk = j * 16 + m16;
                bf16x8 kf0 = *(const bf16x8*)&Kb[buf][rk][sw0];
                bf16x8 kf1 = *(const bf16x8*)&Kb[buf][rk][sw1];
                f32x4 s = (f32x4){0.f, 0.f, 0.f, 0.f};
                s = __builtin_amdgcn_mfma_f32_16x16x32_bf16(kf0, q0, s, 0, 0, 0);
                s = __builtin_amdgcn_mfma_f32_16x16x32_bf16(kf1, q1, s, 0, 0, 0);
                sv[j] = s;
            }
            __builtin_amdgcn_s_setprio(0);

            // ---- V fragments from LDS (issued before softmax; latency hides) ----
            bf16x8 vf[4][2];
            #pragma unroll
            for (int jd = 0; jd < 4; jd++) {
                const int rv = jd * 16 + m16;
                vf[jd][0] = *(const bf16x8*)&Vb[buf][rv][sw0];
                vf[jd][1] = *(const bf16x8*)&Vb[buf][rv][sw1];
            }

            // ---- online softmax (lane-local q-row, scalar m/l) ----
            bf16x8 p0, p1;
            softmax_update_sw(sv, m, l, acc, kt == qt, wave16, quad, m16, Pw, p0, p1);

            // ---- O += P V ----
            __builtin_amdgcn_s_setprio(1);
            #pragma unroll
            for (int jd = 0; jd < 4; jd++) {
                acc[jd] = __builtin_amdgcn_mfma_f32_16x16x32_bf16(p0, vf[jd][0], acc[jd], 0, 0, 0);
                acc[jd] = __builtin_amdgcn_mfma_f32_16x16x32_bf16(p1, vf[jd][1], acc[jd], 0, 0, 0);
            }
            __builtin_amdgcn_s_setprio(0);
        }

        // my ds ops retired -> after the barrier the buffers may be overwritten
        asm volatile("s_waitcnt lgkmcnt(0)" ::: "memory");
        __builtin_amdgcn_s_barrier();
    }
    #undef STAGE

    // epilogue: O / l — l lives at lane q=m16; acc rows are q=quad*4+r
    float linv[4];
    #pragma unroll
    for (int r = 0; r < 4; r++) linv[r] = 1.0f / __shfl(l, quad * 4 + r, 16);
    #pragma unroll
    for (int jd = 0; jd < 4; jd++)
        #pragma unroll
        for (int r = 0; r < 4; r++) {
            const int row = b * Sn + qt * 64 + wave16 + quad * 4 + r;
            o[(size_t)row * Dn + h * DKn + jd * 16 + m16] = (__bf16)(acc[jd][r] * linv[r]);
        }
}

// ---------------------------------------------------------------------------
// Residual + LayerNorm, wave-per-row, barrier-free.
// Lane owns 8 consecutive cols (bf16x8 loads). 64-lane shfl_xor reductions.
// FINAL=0: xb = LN(t + xb) (bf16). FINAL=1: outf = LN(t + xb) (fp32).
// ---------------------------------------------------------------------------
template <int FINAL>
__global__ __launch_bounds__(256) void k_residual_ln(
    const __bf16* __restrict__ t, __bf16* __restrict__ xb,
    const float* __restrict__ g, const float* __restrict__ be,
    float* __restrict__ outf)
{
    const int row  = (blockIdx.x << 2) | (threadIdx.x >> 6);  // 4 rows/block
    const int lane = threadIdx.x & 63;
    const size_t base = (size_t)row * Dn + lane * 8;

    bf16x8 tv = *(const bf16x8*)&t[base];
    bf16x8 xv = *(const bf16x8*)&xb[base];
    float v[8];
    float s = 0.f;
    #pragma unroll
    for (int i = 0; i < 8; i++) {
        v[i] = (float)tv[i] + (float)xv[i];
        s += v[i];
    }
    #pragma unroll
    for (int off = 1; off < 64; off <<= 1) s += __shfl_xor(s, off);
    const float mean = s * (1.0f / Dn);

    float vs = 0.f;
    #pragma unroll
    for (int i = 0; i < 8; i++) {
        v[i] -= mean;
        vs += v[i] * v[i];
    }
    #pragma unroll
    for (int off = 1; off < 64; off <<= 1) vs += __shfl_xor(vs, off);
    const float inv = rsqrtf(vs * (1.0f / Dn) + 1e-5f);

    const f32x4 g0 = *(const f32x4*)&g[lane * 8];
    const f32x4 g1 = *(const f32x4*)&g[lane * 8 + 4];
    const f32x4 b0 = *(const f32x4*)&be[lane * 8];
    const f32x4 b1 = *(const f32x4*)&be[lane * 8 + 4];

    if (FINAL) {
        f32x4 o0, o1;
        #pragma unroll
        for (int i = 0; i < 4; i++) {
            o0[i] = v[i] * inv * g0[i] + b0[i];
            o1[i] = v[i + 4] * inv * g1[i] + b1[i];
        }
        *(f32x4*)&outf[base]     = o0;
        *(f32x4*)&outf[base + 4] = o1;
    } else {
        bf16x8 ov;
        #pragma unroll
        for (int i = 0; i < 4; i++) {
            ov[i]     = (__bf16)(v[i] * inv * g0[i] + b0[i]);
            ov[i + 4] = (__bf16)(v[i + 4] * inv * g1[i] + b1[i]);
        }
        *(bf16x8*)&xb[base] = ov;
    }
}

// ---------------------------------------------------------------------------
// launcher
// ---------------------------------------------------------------------------
extern "C" void kernel_launch(void* const* d_in, const int* in_sizes, int n_in,
                              void* d_out, int out_size, void* d_ws, size_t ws_size,
                              hipStream_t stream)
{
    const float* x_in   = (const float*)d_in[0];
    const float* qkv_w  = (const float*)d_in[1];
    const float* qkv_b  = (const float*)d_in[2];
    const float* out_w  = (const float*)d_in[3];
    const float* out_b  = (const float*)d_in[4];
    const float* ln1_g  = (const float*)d_in[5];
    const float* ln1_b  = (const float*)d_in[6];
    const float* mlp_w1 = (const float*)d_in[7];
    const float* mlp_b1 = (const float*)d_in[8];
    const float* mlp_w2 = (const float*)d_in[9];
    const float* mlp_b2 = (const float*)d_in[10];
    const float* ln2_g  = (const float*)d_in[11];
    const float* ln2_b  = (const float*)d_in[12];

    // workspace layout (~116 MB); residual lives in bf16 Xb only
    char* p = (char*)d_ws;
    __bf16* Xb    = (__bf16*)p; p += (size_t)Mn * Dn * 2;            //  8 MB
    __bf16* QKVb  = (__bf16*)p; p += (size_t)Mn * 3 * Dn * 2;        // 24 MB
    __bf16* AOb   = (__bf16*)p; p += (size_t)Mn * Dn * 2;            //  8 MB
    __bf16* Hb    = (__bf16*)p; p += (size_t)Mn * DFFn * 2;          // 32 MB
    __bf16* BUF3b = (__bf16*)p; p += (size_t)Mn * Dn * 2;            //  8 MB pre-LN temp
    __bf16* Wq    = (__bf16*)p; p += (size_t)Ln * 3 * Dn * Dn * 2;   //  9 MB
    __bf16* Wo    = (__bf16*)p; p += (size_t)Ln * Dn * Dn * 2;       //  3 MB
    __bf16* W1    = (__bf16*)p; p += (size_t)Ln * DFFn * Dn * 2;     // 12 MB
    __bf16* W2    = (__bf16*)p; p += (size_t)Ln * Dn * DFFn * 2;     // 12 MB
    __bf16* Vt    = Hb;   // 8 MB, aliased: Hb dead during attention

    k_cast_bf16<<<(Mn * Dn) / 256, 256, 0, stream>>>(x_in, Xb, Mn * Dn);

    // ALL weight transposes for all 6 layers in one launch (loop-invariant)
    k_trans_all<<<Ln * 3072, dim3(32, 8), 0, stream>>>(
        qkv_w, out_w, mlp_w1, mlp_w2, Wq, Wo, W1, W2);

    for (int l = 0; l < Ln; l++) {
        const __bf16* Wql = Wq + (size_t)l * 3 * Dn * Dn;
        const __bf16* Wol = Wo + (size_t)l * Dn * Dn;
        const __bf16* W1l = W1 + (size_t)l * DFFn * Dn;
        const __bf16* W2l = W2 + (size_t)l * Dn * DFFn;

        // QKV projection -> bf16 [M,1536] + fused Vt scatter (V only to Vt)
        k_gemm_mfma<0, 1, 4, 1, 64><<<768, 256, 0, stream>>>(
            Xb, Wql, qkv_b + (size_t)l * 3 * Dn, QKVb, Vt, Mn, 3 * Dn, Dn, 12);
        // MFMA flash attention (pair split, counted vmcnt, swapped QK) -> bf16
        k_attn_mfma<<<512, 512, 0, stream>>>(QKVb, Vt, AOb);
        // output projection -> bf16 BUF3b  (BK=128: halved barrier drains)
        k_gemm_mfma<0, 1, 2, 0, 128><<<512, 256, 0, stream>>>(
            AOb, Wol, out_b + (size_t)l * Dn, BUF3b, nullptr, Mn, Dn, Dn, 8);
        // x = LN(proj + x)   (bf16 in/out, fp32 math, wave-per-row)
        k_residual_ln<0><<<Mn / 4, 256, 0, stream>>>(BUF3b, Xb,
            ln1_g + (size_t)l * Dn, ln1_b + (size_t)l * Dn, nullptr);
        // MLP up + ReLU -> bf16 [M,2048]  (overwrites Vt alias; attn done)
        k_gemm_mfma<1, 1, 4, 0, 64><<<1024, 256, 0, stream>>>(
            Xb, W1l, mlp_b1 + (size_t)l * DFFn, Hb, nullptr, Mn, DFFn, Dn, 16);
        // MLP down -> bf16 BUF3b  (BK=128)
        k_gemm_mfma<0, 1, 2, 0, 128><<<512, 256, 0, stream>>>(
            Hb, W2l, mlp_b2 + (size_t)l * Dn, BUF3b, nullptr, Mn, Dn, DFFn, 8);
        // x = LN(x + mlp); final layer writes fp32 straight to d_out
        if (l == Ln - 1)
            k_residual_ln<1><<<Mn / 4, 256, 0, stream>>>(BUF3b, Xb,
                ln2_g + (size_t)l * Dn, ln2_b + (size_t)l * Dn, (float*)d_out);
        else
            k_residual_ln<0><<<Mn / 4, 256, 0, stream>>>(BUF3b, Xb,
                ln2_g + (size_t)l * Dn, ln2_b + (size_t)l * Dn, nullptr);
    }
}

// Round 13
// 844.413 us; speedup vs baseline: 1.1042x; 1.0428x over previous
//
#include <hip/hip_runtime.h>
#include <math.h>

// Problem constants
#define Bn   8
#define Sn   1024
#define Dn   512
#define Hn   8
#define DKn  64
#define Ln   6
#define DFFn 2048
#define Mn   (Bn * Sn)   // 8192 rows

typedef __bf16 bf16x8 __attribute__((ext_vector_type(8)));
typedef __bf16 bf16x4 __attribute__((ext_vector_type(4)));
typedef float  f32x4  __attribute__((ext_vector_type(4)));

// async global->LDS, 16B per lane. LDS dest must be wave-uniform base + lane*16.
__device__ __forceinline__ void gl_lds16(const void* g, void* l) {
    __builtin_amdgcn_global_load_lds(
        (const __attribute__((address_space(1))) void*)g,
        (__attribute__((address_space(3))) void*)l, 16, 0, 0);
}

// ---------------------------------------------------------------------------
// fp32 -> bf16 cast (input)
// ---------------------------------------------------------------------------
__global__ __launch_bounds__(256) void k_cast_bf16(const float* __restrict__ in,
                                                   __bf16* __restrict__ out, int n) {
    int i = blockIdx.x * 256 + threadIdx.x;
    if (i < n) out[i] = (__bf16)in[i];
}

// ---------------------------------------------------------------------------
// ALL weight matrices of ALL 6 layers: W[K][N] fp32 -> Wt[N][K] bf16.
// One launch (weights are layer-loop invariant). 32x32 tiles, 32x8 threads.
// ---------------------------------------------------------------------------
__global__ __launch_bounds__(256) void k_trans_all(
    const float* __restrict__ qkv_w, const float* __restrict__ out_w,
    const float* __restrict__ w1, const float* __restrict__ w2,
    __bf16* __restrict__ Wq, __bf16* __restrict__ Wo,
    __bf16* __restrict__ W1o, __bf16* __restrict__ W2o)
{
    const int lay = blockIdx.x / 3072;
    const int t   = blockIdx.x % 3072;
    const float* src; __bf16* dst; int K, N, n0, k0;
    if (t < 768)       { src = qkv_w + (size_t)lay * Dn * 3 * Dn; dst = Wq  + (size_t)lay * 3 * Dn * Dn;
                         K = 512;  N = 1536; int u = t;        n0 = (u % 48) * 32; k0 = (u / 48) * 32; }
    else if (t < 1024) { src = out_w + (size_t)lay * Dn * Dn;     dst = Wo  + (size_t)lay * Dn * Dn;
                         K = 512;  N = 512;  int u = t - 768;  n0 = (u % 16) * 32; k0 = (u / 16) * 32; }
    else if (t < 2048) { src = w1 + (size_t)lay * Dn * DFFn;      dst = W1o + (size_t)lay * DFFn * Dn;
                         K = 512;  N = 2048; int u = t - 1024; n0 = (u % 64) * 32; k0 = (u / 64) * 32; }
    else               { src = w2 + (size_t)lay * DFFn * Dn;      dst = W2o + (size_t)lay * Dn * DFFn;
                         K = 2048; N = 512;  int u = t - 2048; n0 = (u % 16) * 32; k0 = (u / 16) * 32; }

    __shared__ float tt[32][33];
    const int tx = threadIdx.x, ty = threadIdx.y;
    #pragma unroll
    for (int r = 0; r < 4; r++)
        tt[ty + 8 * r][tx] = src[(size_t)(k0 + ty + 8 * r) * N + n0 + tx];
    __syncthreads();
    #pragma unroll
    for (int r = 0; r < 4; r++)
        dst[(size_t)(n0 + ty + 8 * r) * K + k0 + tx] = (__bf16)tt[tx][ty + 8 * r];
}

// ---------------------------------------------------------------------------
// MFMA GEMM: C[M,N] = act(A[M,K]bf16 @ Bt[N,K]bf16^T + bias[N]fp32)
// Block: 256 thr = 4 waves (2x2). Tile: 128 x (JT*32). K-step: BK (64 or 128).
// (a) 1D grid + bijective chunked XCD swizzle.
// (b) XOR LDS swizzle both-sides (rule #21): unit u' = u ^ (row & (UR-1)).
// BK=128 on JT=2 kernels (outproj/MLP-down, grid-limited 2 blocks/CU):
// halved barrier-drain count. R7/R10/R11/R12 evidence: this plain structure
// with unconditional coalesced C-stores is the local optimum — dbuf (R10),
// split-K (R11), and the predicated V-store-skip (R12) all regressed.
// VW=1 (QKV only): cols >=1024 are V -> ALSO scattered into Vt[b*8+h][d][s]
// (dual store: keeping the coalesced QKVb write is faster than predicating).
// ---------------------------------------------------------------------------
template <int RELU, int OUTBF, int JT, int VW, int BK>
__global__ __launch_bounds__(256) void k_gemm_mfma(
    const __bf16* __restrict__ A, const __bf16* __restrict__ Bt,
    const float* __restrict__ bias, void* __restrict__ Cout,
    __bf16* __restrict__ Vt, int M, int N, int K, int NBX)
{
    constexpr int BN = JT * 32;   // 128 or 64
    constexpr int UR = BK / 8;    // 16B units per LDS row
    constexpr int HC = BK / 32;   // K=32 chunks per K-step
    __shared__ __bf16 As[128][BK];
    __shared__ __bf16 Bs[BN][BK];
    const int tid  = threadIdx.x;
    const int lane = tid & 63;
    const int wave = tid >> 6;
    const int wy   = wave >> 1, wx = wave & 1;
    const int m16  = lane & 15, quad = lane >> 4;

    // chunked XCD swizzle (all launches have gridDim.x % 8 == 0)
    const int cpx = gridDim.x >> 3;
    const int id  = (blockIdx.x & 7) * cpx + (blockIdx.x >> 3);
    const int bm  = (id / NBX) * 128;
    const int bn  = (id % NBX) * BN;

    f32x4 acc[4][JT];
    #pragma unroll
    for (int i = 0; i < 4; i++)
        #pragma unroll
        for (int j = 0; j < JT; j++)
            acc[i][j] = (f32x4){0.f, 0.f, 0.f, 0.f};

    const __bf16* Ap = A  + (size_t)bm * K;
    const __bf16* Bp = Bt + (size_t)bn * K;

    // swizzled 16B-unit byte offsets for fragment reads (involution of stage)
    int sw[HC];
    #pragma unroll
    for (int hc = 0; hc < HC; hc++)
        sw[hc] = ((quad + 4 * hc) ^ (m16 & (UR - 1))) * 8;

    for (int k0 = 0; k0 < K; k0 += BK) {
        __syncthreads();
        #pragma unroll
        for (int c = 0; c < UR / 2; c++) {        // A: 128 x UR units
            int lin = tid + c * 256;
            int row = lin / UR, uu = lin % UR;
            int su  = (uu ^ (row & (UR - 1))) << 3;
            gl_lds16(Ap + (size_t)row * K + k0 + su, (void*)(&As[0][0] + lin * 8));
        }
        #pragma unroll
        for (int c = 0; c < (JT * UR) / 8; c++) { // B: BN x UR units
            int lin = tid + c * 256;
            int row = lin / UR, uu = lin % UR;
            int su  = (uu ^ (row & (UR - 1))) << 3;
            gl_lds16(Bp + (size_t)row * K + k0 + su, (void*)(&Bs[0][0] + lin * 8));
        }
        __syncthreads();

        bf16x8 af[4][HC], bfr[JT][HC];
        #pragma unroll
        for (int i = 0; i < 4; i++)
            #pragma unroll
            for (int hc = 0; hc < HC; hc++)
                af[i][hc] = *(const bf16x8*)&As[wy * 64 + i * 16 + m16][sw[hc]];
        #pragma unroll
        for (int j = 0; j < JT; j++)
            #pragma unroll
            for (int hc = 0; hc < HC; hc++)
                bfr[j][hc] = *(const bf16x8*)&Bs[wx * JT * 16 + j * 16 + m16][sw[hc]];
        #pragma unroll
        for (int hc = 0; hc < HC; hc++)
            #pragma unroll
            for (int i = 0; i < 4; i++)
                #pragma unroll
                for (int j = 0; j < JT; j++)
                    acc[i][j] = __builtin_amdgcn_mfma_f32_16x16x32_bf16(
                        af[i][hc], bfr[j][hc], acc[i][j], 0, 0, 0);
    }

    float*  Cf = (float*)Cout;
    __bf16* Cb = (__bf16*)Cout;
    #pragma unroll
    for (int i = 0; i < 4; i++) {
        const int row0 = bm + wy * 64 + i * 16 + quad * 4;
        #pragma unroll
        for (int j = 0; j < JT; j++) {
            const int col = bn + wx * JT * 16 + j * 16 + m16;
            const float bv = bias[col];
            float vv[4];
            #pragma unroll
            for (int r = 0; r < 4; r++) {
                float v = acc[i][j][r] + bv;
                if (RELU) v = fmaxf(v, 0.f);
                vv[r] = v;
                if (OUTBF) Cb[(size_t)(row0 + r) * N + col] = (__bf16)v;
                else       Cf[(size_t)(row0 + r) * N + col] = v;
            }
            if (VW && col >= 1024) {            // V slice -> Vt[b*8+h][d][s]
                const int cc = col - 1024;
                const int bb = row0 >> 10, ss = row0 & 1023;
                bf16x4 pv;
                #pragma unroll
                for (int r = 0; r < 4; r++) pv[r] = (__bf16)vv[r];
                *(bf16x4*)&Vt[((size_t)(bb * Hn + (cc >> 6)) * DKn + (cc & 63)) * Sn + ss] = pv;
            }
        }
    }
}

// ---------------------------------------------------------------------------
// MFMA flash attention (causal), LDS-staged K/V, wave-split tile pair,
// counted vmcnt (T4), SWAPPED QK^T (T12-style lane-local softmax).
// S' = mfma(K_frag, Q_frag): C/D is S'[k=quad*4+r (+j*16)][q=m16]; each
// thread owns one q-row's softmax (scalar m/l, 2 shfl_xor reduce); P-store
// is 4x contiguous 8B; exp in log2 domain. PV reads P as the A-fragment.
// ---------------------------------------------------------------------------
__device__ __forceinline__ void softmax_update_sw(
    f32x4 sv[4], float& m, float& l, f32x4 acc[4],
    bool diag, int wave16, int quad, int m16,
    __bf16 (*Pw)[72], bf16x8& pf0, bf16x8& pf1)
{
    const float SC = 0.125f * 1.44269504089f;   // 1/sqrt(64) * log2(e)
    float pmax = -1e30f;
    #pragma unroll
    for (int j = 0; j < 4; j++)
        #pragma unroll
        for (int r = 0; r < 4; r++) {
            float v = sv[j][r] * SC;
            if (diag && (j * 16 + quad * 4 + r) > (wave16 + m16)) v = -1e30f;
            sv[j][r] = v;
            pmax = fmaxf(pmax, v);
        }
    // cross-quad reduce: lanes {m16, m16+16, m16+32, m16+48} share q=m16
    pmax = fmaxf(pmax, __shfl_xor(pmax, 16));
    pmax = fmaxf(pmax, __shfl_xor(pmax, 32));

    // T13 defer-max (log2 domain; 11.54 = 8*log2e -> P bounded by e^8)
    if (__any((int)(pmax > m + 11.54f))) {
        float mn = fmaxf(m, pmax);
        float al = __builtin_amdgcn_exp2f(m - mn);
        m = mn;
        l *= al;
        float alr[4];
        #pragma unroll
        for (int r = 0; r < 4; r++) alr[r] = __shfl(al, quad * 4 + r, 16);
        #pragma unroll
        for (int j = 0; j < 4; j++)
            #pragma unroll
            for (int r = 0; r < 4; r++) acc[j][r] *= alr[r];
    }

    float rs = 0.f;
    #pragma unroll
    for (int j = 0; j < 4; j++) {
        bf16x4 pw;
        #pragma unroll
        for (int r = 0; r < 4; r++) {
            float p = __builtin_amdgcn_exp2f(sv[j][r] - m);
            rs += p;
            pw[r] = (__bf16)p;
        }
        *(bf16x4*)&Pw[m16][j * 16 + quad * 4] = pw;   // contiguous 8B store
    }
    rs += __shfl_xor(rs, 16);
    rs += __shfl_xor(rs, 32);
    l += rs;

    // per-wave in-order DS: the 4 writes above retire before these reads
    pf0 = *(const bf16x8*)&Pw[m16][quad * 8];
    pf1 = *(const bf16x8*)&Pw[m16][32 + quad * 8];
}

__global__ __launch_bounds__(512, 4) void k_attn_mfma(
    const __bf16* __restrict__ qkv, const __bf16* __restrict__ Vt,
    __bf16* __restrict__ o)
{
    const int id = blockIdx.x;
    const int u  = id >> 6;            // 0..7
    const int pr = (u < 4) ? u : 11 - u;   // CU-pair balance: steps sum to 25
    const int b  = (id >> 3) & 7;
    const int h  = id & 7;             // id%8 = h -> blocks of one h share an XCD
    const int tid  = threadIdx.x;
    const int lane = tid & 63, wave = tid >> 6;   // 0..7
    const int m16  = lane & 15, quad = lane >> 4;
    const int isB  = wave >> 2;        // 0: tile A (qtA=pr), 1: tile B (qtB=15-pr)
    const int wave16 = (wave & 3) * 16;
    const int qtA  = pr, qtB = 15 - pr;
    const int qt   = isB ? qtB : qtA;

    __shared__ __bf16 Kb[2][64][64];     // double-buffered K tile (swizzled)
    __shared__ __bf16 Vb[2][64][64];     // double-buffered V tile (swizzled)
    __shared__ __bf16 Ps[8][16][72];     // per-wave P scratch

    const __bf16* base = qkv + (size_t)b * Sn * 1536 + h * DKn;   // Q +0, K +512
    const __bf16* vtb  = Vt + (size_t)(b * Hn + h) * DKn * Sn;
    __bf16 (*Pw)[72] = Ps[wave];

    // swizzled 16B-unit offsets for fragment reads (involution of stage swizzle)
    const int sw0 = ((quad    ) ^ (m16 & 7)) * 8;
    const int sw1 = ((quad + 4) ^ (m16 & 7)) * 8;

    // staging coords: 512 threads x 16B cover one 64x64 bf16 tile per call.
    // Exactly 2 VMEM ops per thread per STAGE (1 K + 1 V).
    const int srow = tid >> 3;
    const int ssu  = ((tid & 7) ^ (srow & 7)) * 8;

    #define STAGE(KT, BB)                                                       \
        {                                                                       \
            gl_lds16(base + (size_t)((KT) * 64 + srow) * 1536 + 512 + ssu,      \
                     (void*)(&Kb[BB][0][0] + tid * 8));                         \
            gl_lds16(vtb + (size_t)srow * Sn + (KT) * 64 + ssu,                 \
                     (void*)(&Vb[BB][0][0] + tid * 8));                         \
        }

    STAGE(0, 0);   // issue tile-0 staging first; Q loads overlap it

    bf16x8 q0, q1;
    {
        const __bf16* qa = base + (size_t)(qt * 64 + wave16 + m16) * 1536 + quad * 8;
        q0 = *(const bf16x8*)qa; q1 = *(const bf16x8*)(qa + 32);
    }

    float m = -1e30f, l = 0.f;
    f32x4 acc[4];
    #pragma unroll
    for (int r = 0; r < 4; r++) acc[r] = (f32x4){0.f, 0.f, 0.f, 0.f};

    for (int kt = 0; kt <= qtB; kt++) {
        const int buf = kt & 1;
        // issue next-tile staging, then wait only for CURRENT tile's loads:
        // exactly 2 loads (the new stage) remain outstanding across the barrier.
        if (kt < qtB) {
            STAGE(kt + 1, buf ^ 1);
            asm volatile("s_waitcnt vmcnt(2)" ::: "memory");
        } else {
            asm volatile("s_waitcnt vmcnt(0)" ::: "memory");
        }
        __builtin_amdgcn_s_barrier();   // cur buf fully written, all waves aligned

        if (isB || kt <= qtA) {
            // ---- S' = K Q^T from LDS (swapped operands; loads unchanged) ----
            f32x4 sv[4];
            __builtin_amdgcn_s_setprio(1);
            #pragma unroll
            for (int j = 0; j < 4; j++) {
                const int rk = j * 16 + m16;
                bf16x8 kf0 = *(const bf16x8*)&Kb[buf][rk][sw0];
                bf16x8 kf1 = *(const bf16x8*)&Kb[buf][rk][sw1];
                f32x4 s = (f32x4){0.f, 0.f, 0.f, 0.f};
                s = __builtin_amdgcn_mfma_f32_16x16x32_bf16(kf0, q0, s, 0, 0, 0);
                s = __builtin_amdgcn_mfma_f32_16x16x32_bf16(kf1, q1, s, 0, 0, 0);
                sv[j] = s;
            }
            __builtin_amdgcn_s_setprio(0);

            // ---- V fragments from LDS (issued before softmax; latency hides) ----
            bf16x8 vf[4][2];
            #pragma unroll
            for (int jd = 0; jd < 4; jd++) {
                const int rv = jd * 16 + m16;
                vf[jd][0] = *(const bf16x8*)&Vb[buf][rv][sw0];
                vf[jd][1] = *(const bf16x8*)&Vb[buf][rv][sw1];
            }

            // ---- online softmax (lane-local q-row, scalar m/l) ----
            bf16x8 p0, p1;
            softmax_update_sw(sv, m, l, acc, kt == qt, wave16, quad, m16, Pw, p0, p1);

            // ---- O += P V ----
            __builtin_amdgcn_s_setprio(1);
            #pragma unroll
            for (int jd = 0; jd < 4; jd++) {
                acc[jd] = __builtin_amdgcn_mfma_f32_16x16x32_bf16(p0, vf[jd][0], acc[jd], 0, 0, 0);
                acc[jd] = __builtin_amdgcn_mfma_f32_16x16x32_bf16(p1, vf[jd][1], acc[jd], 0, 0, 0);
            }
            __builtin_amdgcn_s_setprio(0);
        }

        // my ds ops retired -> after the barrier the buffers may be overwritten
        asm volatile("s_waitcnt lgkmcnt(0)" ::: "memory");
        __builtin_amdgcn_s_barrier();
    }
    #undef STAGE

    // epilogue: O / l — l lives at lane q=m16; acc rows are q=quad*4+r
    float linv[4];
    #pragma unroll
    for (int r = 0; r < 4; r++) linv[r] = 1.0f / __shfl(l, quad * 4 + r, 16);
    #pragma unroll
    for (int jd = 0; jd < 4; jd++)
        #pragma unroll
        for (int r = 0; r < 4; r++) {
            const int row = b * Sn + qt * 64 + wave16 + quad * 4 + r;
            o[(size_t)row * Dn + h * DKn + jd * 16 + m16] = (__bf16)(acc[jd][r] * linv[r]);
        }
}

// ---------------------------------------------------------------------------
// Residual + LayerNorm, wave-per-row, barrier-free.
// Lane owns 8 consecutive cols (bf16x8 loads). 64-lane shfl_xor reductions.
// FINAL=0: xb = LN(t + xb) (bf16). FINAL=1: outf = LN(t + xb) (fp32).
// ---------------------------------------------------------------------------
template <int FINAL>
__global__ __launch_bounds__(256) void k_residual_ln(
    const __bf16* __restrict__ t, __bf16* __restrict__ xb,
    const float* __restrict__ g, const float* __restrict__ be,
    float* __restrict__ outf)
{
    const int row  = (blockIdx.x << 2) | (threadIdx.x >> 6);  // 4 rows/block
    const int lane = threadIdx.x & 63;
    const size_t base = (size_t)row * Dn + lane * 8;

    bf16x8 tv = *(const bf16x8*)&t[base];
    bf16x8 xv = *(const bf16x8*)&xb[base];
    float v[8];
    float s = 0.f;
    #pragma unroll
    for (int i = 0; i < 8; i++) {
        v[i] = (float)tv[i] + (float)xv[i];
        s += v[i];
    }
    #pragma unroll
    for (int off = 1; off < 64; off <<= 1) s += __shfl_xor(s, off);
    const float mean = s * (1.0f / Dn);

    float vs = 0.f;
    #pragma unroll
    for (int i = 0; i < 8; i++) {
        v[i] -= mean;
        vs += v[i] * v[i];
    }
    #pragma unroll
    for (int off = 1; off < 64; off <<= 1) vs += __shfl_xor(vs, off);
    const float inv = rsqrtf(vs * (1.0f / Dn) + 1e-5f);

    const f32x4 g0 = *(const f32x4*)&g[lane * 8];
    const f32x4 g1 = *(const f32x4*)&g[lane * 8 + 4];
    const f32x4 b0 = *(const f32x4*)&be[lane * 8];
    const f32x4 b1 = *(const f32x4*)&be[lane * 8 + 4];

    if (FINAL) {
        f32x4 o0, o1;
        #pragma unroll
        for (int i = 0; i < 4; i++) {
            o0[i] = v[i] * inv * g0[i] + b0[i];
            o1[i] = v[i + 4] * inv * g1[i] + b1[i];
        }
        *(f32x4*)&outf[base]     = o0;
        *(f32x4*)&outf[base + 4] = o1;
    } else {
        bf16x8 ov;
        #pragma unroll
        for (int i = 0; i < 4; i++) {
            ov[i]     = (__bf16)(v[i] * inv * g0[i] + b0[i]);
            ov[i + 4] = (__bf16)(v[i + 4] * inv * g1[i] + b1[i]);
        }
        *(bf16x8*)&xb[base] = ov;
    }
}

// ---------------------------------------------------------------------------
// launcher
// ---------------------------------------------------------------------------
extern "C" void kernel_launch(void* const* d_in, const int* in_sizes, int n_in,
                              void* d_out, int out_size, void* d_ws, size_t ws_size,
                              hipStream_t stream)
{
    const float* x_in   = (const float*)d_in[0];
    const float* qkv_w  = (const float*)d_in[1];
    const float* qkv_b  = (const float*)d_in[2];
    const float* out_w  = (const float*)d_in[3];
    const float* out_b  = (const float*)d_in[4];
    const float* ln1_g  = (const float*)d_in[5];
    const float* ln1_b  = (const float*)d_in[6];
    const float* mlp_w1 = (const float*)d_in[7];
    const float* mlp_b1 = (const float*)d_in[8];
    const float* mlp_w2 = (const float*)d_in[9];
    const float* mlp_b2 = (const float*)d_in[10];
    const float* ln2_g  = (const float*)d_in[11];
    const float* ln2_b  = (const float*)d_in[12];

    // workspace layout (~116 MB); residual lives in bf16 Xb only
    char* p = (char*)d_ws;
    __bf16* Xb    = (__bf16*)p; p += (size_t)Mn * Dn * 2;            //  8 MB
    __bf16* QKVb  = (__bf16*)p; p += (size_t)Mn * 3 * Dn * 2;        // 24 MB
    __bf16* AOb   = (__bf16*)p; p += (size_t)Mn * Dn * 2;            //  8 MB
    __bf16* Hb    = (__bf16*)p; p += (size_t)Mn * DFFn * 2;          // 32 MB
    __bf16* BUF3b = (__bf16*)p; p += (size_t)Mn * Dn * 2;            //  8 MB pre-LN temp
    __bf16* Wq    = (__bf16*)p; p += (size_t)Ln * 3 * Dn * Dn * 2;   //  9 MB
    __bf16* Wo    = (__bf16*)p; p += (size_t)Ln * Dn * Dn * 2;       //  3 MB
    __bf16* W1    = (__bf16*)p; p += (size_t)Ln * DFFn * Dn * 2;     // 12 MB
    __bf16* W2    = (__bf16*)p; p += (size_t)Ln * Dn * DFFn * 2;     // 12 MB
    __bf16* Vt    = Hb;   // 8 MB, aliased: Hb dead during attention

    k_cast_bf16<<<(Mn * Dn) / 256, 256, 0, stream>>>(x_in, Xb, Mn * Dn);

    // ALL weight transposes for all 6 layers in one launch (loop-invariant)
    k_trans_all<<<Ln * 3072, dim3(32, 8), 0, stream>>>(
        qkv_w, out_w, mlp_w1, mlp_w2, Wq, Wo, W1, W2);

    for (int l = 0; l < Ln; l++) {
        const __bf16* Wql = Wq + (size_t)l * 3 * Dn * Dn;
        const __bf16* Wol = Wo + (size_t)l * Dn * Dn;
        const __bf16* W1l = W1 + (size_t)l * DFFn * Dn;
        const __bf16* W2l = W2 + (size_t)l * Dn * DFFn;

        // QKV projection -> bf16 [M,1536] + fused Vt scatter (dual store)
        k_gemm_mfma<0, 1, 4, 1, 64><<<768, 256, 0, stream>>>(
            Xb, Wql, qkv_b + (size_t)l * 3 * Dn, QKVb, Vt, Mn, 3 * Dn, Dn, 12);
        // MFMA flash attention (pair split, counted vmcnt, swapped QK) -> bf16
        k_attn_mfma<<<512, 512, 0, stream>>>(QKVb, Vt, AOb);
        // output projection -> bf16 BUF3b  (BK=128: halved barrier drains)
        k_gemm_mfma<0, 1, 2, 0, 128><<<512, 256, 0, stream>>>(
            AOb, Wol, out_b + (size_t)l * Dn, BUF3b, nullptr, Mn, Dn, Dn, 8);
        // x = LN(proj + x)   (bf16 in/out, fp32 math, wave-per-row)
        k_residual_ln<0><<<Mn / 4, 256, 0, stream>>>(BUF3b, Xb,
            ln1_g + (size_t)l * Dn, ln1_b + (size_t)l * Dn, nullptr);
        // MLP up + ReLU -> bf16 [M,2048]  (overwrites Vt alias; attn done)
        k_gemm_mfma<1, 1, 4, 0, 64><<<1024, 256, 0, stream>>>(
            Xb, W1l, mlp_b1 + (size_t)l * DFFn, Hb, nullptr, Mn, DFFn, Dn, 16);
        // MLP down -> bf16 BUF3b  (BK=128)
        k_gemm_mfma<0, 1, 2, 0, 128><<<512, 256, 0, stream>>>(
            Hb, W2l, mlp_b2 + (size_t)l * Dn, BUF3b, nullptr, Mn, Dn, DFFn, 8);
        // x = LN(x + mlp); final layer writes fp32 straight to d_out
        if (l == Ln - 1)
            k_residual_ln<1><<<Mn / 4, 256, 0, stream>>>(BUF3b, Xb,
                ln2_g + (size_t)l * Dn, ln2_b + (size_t)l * Dn, (float*)d_out);
        else
            k_residual_ln<0><<<Mn / 4, 256, 0, stream>>>(BUF3b, Xb,
                ln2_g + (size_t)l * Dn, ln2_b + (size_t)l * Dn, nullptr);
    }
}